// Round 10
// baseline (327.173 us; speedup 1.0000x reference)
//
#include <hip/hip_runtime.h>
#include <cfloat>

// Problem constants: M=N=64 grid, DIM=512, B=4096, SIGMA=32
#define DIMK 512
#define MN   4096
#define BATCH 4096
#define BK 32

typedef _Float16 half8_t __attribute__((ext_vector_type(8)));
typedef float f32x4 __attribute__((ext_vector_type(4)));

// async global->LDS, 16B per lane; LDS dest is wave-uniform base + lane*16
#define GLD16(gp, lp) __builtin_amdgcn_global_load_lds( \
    (const __attribute__((address_space(1))) void*)(gp), \
    (__attribute__((address_space(3))) void*)(lp), 16, 0, 0)

// ---------------------------------------------------------------------------
// fp32 -> (hi, mid) f16 split: a = hi + mid + O(2^-22 |a|).
// 2048 blocks: [0,1024) convert X, [1024,2048) convert W + w2 row sums.
// Blocks 0..15 also re-init minv (4096 u64 -> ~0), block 16 re-inits the
// 32 per-band counters (must happen every call: ws is re-poisoned).
// ---------------------------------------------------------------------------
__global__ __launch_bounds__(256) void convert_kernel(
        const float* __restrict__ X, const float* __restrict__ W,
        _Float16* __restrict__ Xhi, _Float16* __restrict__ Xmi,
        _Float16* __restrict__ Whi, _Float16* __restrict__ Wmi,
        float* __restrict__ w2,
        unsigned long long* __restrict__ minv, int* __restrict__ cnt) {
    const int blk  = blockIdx.x;
    const int t    = threadIdx.x;
    if (blk < 16)               minv[blk * 256 + t] = ~0ull;
    if (blk == 16 && t < 32)    cnt[t] = 0;

    const bool isW = blk >= 1024;
    const float* src = isW ? W : X;
    _Float16* hi  = isW ? Whi : Xhi;
    _Float16* mid = isW ? Wmi : Xmi;
    const size_t idx = (size_t)(isW ? blk - 1024 : blk) * 2048 + (size_t)t * 8;

    float4 v0 = *(const float4*)(src + idx);
    float4 v1 = *(const float4*)(src + idx + 4);
    float v[8] = {v0.x, v0.y, v0.z, v0.w, v1.x, v1.y, v1.z, v1.w};
    half8_t hv, mv;
    float s = 0.f;
#pragma unroll
    for (int e = 0; e < 8; e++) {
        s += v[e] * v[e];
        _Float16 h = (_Float16)v[e];
        hv[e] = h;
        mv[e] = (_Float16)(v[e] - (float)h);
    }
    *(half8_t*)(hi + idx) = hv;
    *(half8_t*)(mid + idx) = mv;

    if (isW) {
        // one wave covers exactly one row of 512: reduce s across 64 lanes
#pragma unroll
        for (int o = 32; o > 0; o >>= 1) s += __shfl_down(s, o);
        if ((t & 63) == 0) {
            int row = (blk - 1024) * 4 + (t >> 6);
            w2[row] = s;
        }
    }
}

// ---------------------------------------------------------------------------
// Fused score+epilogue kernel.
// Score: s[b,k] = w2[k] - 2*dot(X[b],W[k]) via 3-product f16 hi/mid split,
// R8 structure (128x128 tile, BK=32, dbuf LDS 64KB, 1 barrier/iter).
// Argmin: per-row best packed as (monotone_fp32(s) << 32 | col) and
// atomicMin'd into minv[row] — lexicographic min == value min with
// lowest-index tie-break (matches jnp.argmin).
// Epilogue: per m-band counter; the last of the 32 n-blocks re-reads the
// band's keys (device-scope) and writes the 128 x 4096 Gaussian rows,
// overlapping with still-running score blocks.
// ---------------------------------------------------------------------------
__global__ __launch_bounds__(256, 2) void score_kernel(
        const _Float16* __restrict__ Xhi, const _Float16* __restrict__ Xmi,
        const _Float16* __restrict__ Whi, const _Float16* __restrict__ Wmi,
        const float* __restrict__ w2,
        unsigned long long* __restrict__ minv, int* __restrict__ cnt,
        const int* __restrict__ decay_p, const int* __restrict__ it_p,
        float* __restrict__ out) {
    // 64 KB: two buffers, each Ah|Am|Bh|Bm (4096 f16 = 8KB each)
    __shared__ __align__(16) _Float16 lds[2][16384];
    __shared__ int sflag;

    const int t    = threadIdx.x;
    const int lane = t & 63;
    const int w    = t >> 6;        // wave 0..3
    const int wm   = w >> 1;        // wave m-half
    const int wn   = w & 1;         // wave n-half
    const int m0   = blockIdx.y * 128;
    const int n0   = blockIdx.x * 128;

    f32x4 acc[4][4];
#pragma unroll
    for (int i = 0; i < 4; i++)
#pragma unroll
        for (int j = 0; j < 4; j++) acc[i][j] = (f32x4){0.f, 0.f, 0.f, 0.f};

    // staging: wave w loads 16-row blocks (2w, 2w+1) of each of the 4 arrays.
    // within a 1KB block: lane l -> row (l&15), k-octet (l>>4).
    const int r16 = lane & 15;
    const int kg  = lane >> 4;
    const int b0  = 2 * w, b1 = 2 * w + 1;
    const size_t ko = (size_t)kg * 8;
    const _Float16* gA[4];
    const _Float16* gB[4];
    gA[0] = Xhi + (size_t)(m0 + b0 * 16 + r16) * DIMK + ko;
    gA[1] = Xhi + (size_t)(m0 + b1 * 16 + r16) * DIMK + ko;
    gA[2] = Xmi + (size_t)(m0 + b0 * 16 + r16) * DIMK + ko;
    gA[3] = Xmi + (size_t)(m0 + b1 * 16 + r16) * DIMK + ko;
    gB[0] = Whi + (size_t)(n0 + b0 * 16 + r16) * DIMK + ko;
    gB[1] = Whi + (size_t)(n0 + b1 * 16 + r16) * DIMK + ko;
    gB[2] = Wmi + (size_t)(n0 + b0 * 16 + r16) * DIMK + ko;
    gB[3] = Wmi + (size_t)(n0 + b1 * 16 + r16) * DIMK + ko;
    const int dA[4] = {b0 * 512, b1 * 512, 4096 + b0 * 512, 4096 + b1 * 512};
    const int dB[4] = {8192 + b0 * 512, 8192 + b1 * 512,
                       12288 + b0 * 512, 12288 + b1 * 512};

    // prologue: fill buffer 0 with tile k=0
#pragma unroll
    for (int p = 0; p < 4; p++) {
        GLD16(gA[p], &lds[0][dA[p]]);
        GLD16(gB[p], &lds[0][dB[p]]);
    }

    int cur = 0;
    for (int k0 = 0; k0 < DIMK; k0 += BK) {
        __syncthreads();               // lds[cur] staged; prior frag reads done
        if (k0 + BK < DIMK) {          // prefetch next tile into alternate buf
            int nk = k0 + BK;
#pragma unroll
            for (int p = 0; p < 4; p++) {
                GLD16(gA[p] + nk, &lds[cur ^ 1][dA[p]]);
                GLD16(gB[p] + nk, &lds[cur ^ 1][dB[p]]);
            }
        }
        const _Float16* sAh = &lds[cur][0];
        const _Float16* sAm = &lds[cur][4096];
        const _Float16* sBh = &lds[cur][8192];
        const _Float16* sBm = &lds[cur][12288];

        half8_t ah[4], am[4], bh[4], bm[4];
#pragma unroll
        for (int i = 0; i < 4; i++) {
            ah[i] = *(const half8_t*)(sAh + (wm * 4 + i) * 512 + lane * 8);
            am[i] = *(const half8_t*)(sAm + (wm * 4 + i) * 512 + lane * 8);
            bh[i] = *(const half8_t*)(sBh + (wn * 4 + i) * 512 + lane * 8);
            bm[i] = *(const half8_t*)(sBm + (wn * 4 + i) * 512 + lane * 8);
        }
#pragma unroll
        for (int i = 0; i < 4; i++)
#pragma unroll
            for (int j = 0; j < 4; j++) {
                acc[i][j] = __builtin_amdgcn_mfma_f32_16x16x32_f16(am[i], bh[j], acc[i][j], 0, 0, 0);
                acc[i][j] = __builtin_amdgcn_mfma_f32_16x16x32_f16(ah[i], bm[j], acc[i][j], 0, 0, 0);
                acc[i][j] = __builtin_amdgcn_mfma_f32_16x16x32_f16(ah[i], bh[j], acc[i][j], 0, 0, 0);
            }
        cur ^= 1;
    }

    // ---- per-row argmin over this wave's 64 cols -> packed atomicMin ----
    // D layout: col = lane&15, row = (lane>>4)*4 + v   (m89/m91 verified)
    const int q  = lane >> 4;
    const int cl = lane & 15;
    float w2v[4];
    int   ncol[4];
#pragma unroll
    for (int j = 0; j < 4; j++) {
        ncol[j] = n0 + wn * 64 + j * 16 + cl;
        w2v[j]  = w2[ncol[j]];
    }
#pragma unroll
    for (int i = 0; i < 4; i++)
#pragma unroll
        for (int v = 0; v < 4; v++) {
            float bv = FLT_MAX;
            int   bi = 0x7FFFFFFF;
#pragma unroll
            for (int j = 0; j < 4; j++) {        // j ascending -> ties keep lower n
                float s = w2v[j] - 2.0f * acc[i][j][v];
                if (s < bv) { bv = s; bi = ncol[j]; }
            }
#pragma unroll
            for (int mask = 1; mask <= 8; mask <<= 1) {   // reduce over 16 col-lanes
                float ov = __shfl_xor(bv, mask);
                int   oi = __shfl_xor(bi, mask);
                if (ov < bv || (ov == bv && oi < bi)) { bv = ov; bi = oi; }
            }
            if (cl == 0) {
                int m = m0 + wm * 64 + i * 16 + q * 4 + v;
                unsigned u = __float_as_uint(bv);
                unsigned mono = (u & 0x80000000u) ? ~u : (u | 0x80000000u);
                unsigned long long key =
                    ((unsigned long long)mono << 32) | (unsigned)bi;
                atomicMin(&minv[m], key);
            }
        }

    // ---- last-block-done: write this m-band's Gaussian output ----
    __threadfence();               // release: our atomics visible before count
    __syncthreads();               // also: LDS reuse below is now safe
    if (t == 0) {
        int old = atomicAdd(&cnt[blockIdx.y], 1);
        sflag = (old == 31);
    }
    __syncthreads();
    if (!sflag) return;

    __threadfence();               // acquire
    unsigned long long* keys = (unsigned long long*)&lds[0][0];
    if (t < 128)                   // device-scope read via no-op atomicMin
        keys[t] = atomicMin(&minv[m0 + t], ~0ull);
    __syncthreads();

    const float lr  = __expf(-(float)(*it_p) / (float)(*decay_p));
    const float so  = 32.0f * lr;          // SIGMA = 32
    const float inv = 1.0f / (so * so);
    // wave w handles rows m0 + w*32 .. +32; per row, lane l holds er[l], ec[l]
    for (int rr = 0; rr < 32; rr++) {
        const int row = w * 32 + rr;
        const unsigned idx = (unsigned)(keys[row] & 0xFFFFFFFFull);
        const int r = idx >> 6, c = idx & 63;
        float dr = (float)(lane - r), dc = (float)(lane - c);
        float er_l = __expf(-dr * dr * inv);
        float ec_l = __expf(-dc * dc * inv);
        float4* orow = (float4*)(out + (size_t)(m0 + row) * 4096);
#pragma unroll 4
        for (int itn = 0; itn < 16; itn++) {
            int f  = itn * 64 + lane;     // float4 index in the 4096-row
            int i  = f >> 4;
            int j0 = (f & 15) * 4;
            float e = __shfl(er_l, i);
            float4 o;
            o.x = e * __shfl(ec_l, j0);
            o.y = e * __shfl(ec_l, j0 + 1);
            o.z = e * __shfl(ec_l, j0 + 2);
            o.w = e * __shfl(ec_l, j0 + 3);
            orow[f] = o;
        }
    }
}

// ---------------------------------------------------------------------------
extern "C" void kernel_launch(void* const* d_in, const int* in_sizes, int n_in,
                              void* d_out, int out_size, void* d_ws, size_t ws_size,
                              hipStream_t stream) {
    const float* X       = (const float*)d_in[0];   // [4096,512]
    const float* W       = (const float*)d_in[1];   // [4096,512]
    const int*   decay_p = (const int*)d_in[3];
    const int*   it_p    = (const int*)d_in[4];
    float* out = (float*)d_out;

    // ws: Xhi|Xmi|Whi|Wmi (4MB each f16) | w2 16KB | minv 32KB | cnt 128B
    _Float16* Xhi = (_Float16*)d_ws;
    _Float16* Xmi = Xhi + (size_t)BATCH * DIMK;
    _Float16* Whi = Xmi + (size_t)BATCH * DIMK;
    _Float16* Wmi = Whi + (size_t)MN * DIMK;
    float*    w2  = (float*)(Wmi + (size_t)MN * DIMK);
    unsigned long long* minv = (unsigned long long*)(w2 + MN);
    int*      cnt = (int*)(minv + MN);

    convert_kernel<<<2048, 256, 0, stream>>>(X, W, Xhi, Xmi, Whi, Wmi, w2,
                                             minv, cnt);
    score_kernel<<<dim3(32, 32), 256, 0, stream>>>(Xhi, Xmi, Whi, Wmi, w2,
                                                   minv, cnt, decay_p, it_p, out);
}

// Round 12
// 172.014 us; speedup vs baseline: 1.9020x; 1.9020x over previous
//
#include <hip/hip_runtime.h>
#include <cfloat>

// Problem constants: M=N=64 grid, DIM=512, B=4096, SIGMA=32
#define DIMK 512
#define MN   4096
#define BATCH 4096
#define BK 32
#define NCHUNK 64   // per-row argmin partials: 64 chunks of 64 cols

typedef _Float16 half8_t __attribute__((ext_vector_type(8)));
typedef float f32x4 __attribute__((ext_vector_type(4)));

// async global->LDS, 16B per lane; LDS dest is wave-uniform base + lane*16
#define GLD16(gp, lp) __builtin_amdgcn_global_load_lds( \
    (const __attribute__((address_space(1))) void*)(gp), \
    (__attribute__((address_space(3))) void*)(lp), 16, 0, 0)

// ---------------------------------------------------------------------------
// fp32 -> (hi, mid) f16 split: a = hi + mid + O(2^-22 |a|).
// 2048 blocks: [0,1024) convert X, [1024,2048) convert W + w2 row sums.
// (unchanged from the 172.74us baseline)
// ---------------------------------------------------------------------------
__global__ __launch_bounds__(256) void convert_kernel(
        const float* __restrict__ X, const float* __restrict__ W,
        _Float16* __restrict__ Xhi, _Float16* __restrict__ Xmi,
        _Float16* __restrict__ Whi, _Float16* __restrict__ Wmi,
        float* __restrict__ w2) {
    const int blk  = blockIdx.x;
    const int t    = threadIdx.x;
    const bool isW = blk >= 1024;
    const float* src = isW ? W : X;
    _Float16* hi  = isW ? Whi : Xhi;
    _Float16* mid = isW ? Wmi : Xmi;
    const size_t idx = (size_t)(isW ? blk - 1024 : blk) * 2048 + (size_t)t * 8;

    float4 v0 = *(const float4*)(src + idx);
    float4 v1 = *(const float4*)(src + idx + 4);
    float v[8] = {v0.x, v0.y, v0.z, v0.w, v1.x, v1.y, v1.z, v1.w};
    half8_t hv, mv;
    float s = 0.f;
#pragma unroll
    for (int e = 0; e < 8; e++) {
        s += v[e] * v[e];
        _Float16 h = (_Float16)v[e];
        hv[e] = h;
        mv[e] = (_Float16)(v[e] - (float)h);
    }
    *(half8_t*)(hi + idx) = hv;
    *(half8_t*)(mid + idx) = mv;

    if (isW) {
        // one wave covers exactly one row of 512: reduce s across 64 lanes
#pragma unroll
        for (int o = 32; o > 0; o >>= 1) s += __shfl_down(s, o);
        if ((t & 63) == 0) {
            int row = (blk - 1024) * 4 + (t >> 6);
            w2[row] = s;
        }
    }
}

// ---------------------------------------------------------------------------
// MFMA score kernel (172.74us baseline, unchanged): 3-product f16 hi/mid
// split, 128x128 tile, BK=32, dbuf LDS 64KB, 1 barrier/iter, product-major
// MFMA order.
// ---------------------------------------------------------------------------
__global__ __launch_bounds__(256, 2) void score_kernel(
        const _Float16* __restrict__ Xhi, const _Float16* __restrict__ Xmi,
        const _Float16* __restrict__ Whi, const _Float16* __restrict__ Wmi,
        const float* __restrict__ w2,
        float* __restrict__ pval, int* __restrict__ pidx) {
    // 64 KB: two buffers, each Ah|Am|Bh|Bm (4096 f16 = 8KB each)
    __shared__ __align__(16) _Float16 lds[2][16384];

    const int t    = threadIdx.x;
    const int lane = t & 63;
    const int w    = t >> 6;        // wave 0..3
    const int wm   = w >> 1;        // wave m-half
    const int wn   = w & 1;         // wave n-half
    const int m0   = blockIdx.y * 128;
    const int n0   = blockIdx.x * 128;

    f32x4 acc[4][4];
#pragma unroll
    for (int i = 0; i < 4; i++)
#pragma unroll
        for (int j = 0; j < 4; j++) acc[i][j] = (f32x4){0.f, 0.f, 0.f, 0.f};

    // staging: wave w loads 16-row blocks (2w, 2w+1) of each of the 4 arrays.
    // within a 1KB block: lane l -> row (l&15), k-octet (l>>4).
    const int r16 = lane & 15;
    const int kg  = lane >> 4;
    const int b0  = 2 * w, b1 = 2 * w + 1;
    const size_t ko = (size_t)kg * 8;
    const _Float16* gA[4];
    const _Float16* gB[4];
    gA[0] = Xhi + (size_t)(m0 + b0 * 16 + r16) * DIMK + ko;
    gA[1] = Xhi + (size_t)(m0 + b1 * 16 + r16) * DIMK + ko;
    gA[2] = Xmi + (size_t)(m0 + b0 * 16 + r16) * DIMK + ko;
    gA[3] = Xmi + (size_t)(m0 + b1 * 16 + r16) * DIMK + ko;
    gB[0] = Whi + (size_t)(n0 + b0 * 16 + r16) * DIMK + ko;
    gB[1] = Whi + (size_t)(n0 + b1 * 16 + r16) * DIMK + ko;
    gB[2] = Wmi + (size_t)(n0 + b0 * 16 + r16) * DIMK + ko;
    gB[3] = Wmi + (size_t)(n0 + b1 * 16 + r16) * DIMK + ko;
    // LDS dest offsets (f16 units) within a buffer: Ah@0 Am@4096 Bh@8192 Bm@12288
    const int dA[4] = {b0 * 512, b1 * 512, 4096 + b0 * 512, 4096 + b1 * 512};
    const int dB[4] = {8192 + b0 * 512, 8192 + b1 * 512,
                       12288 + b0 * 512, 12288 + b1 * 512};

    // prologue: fill buffer 0 with tile k=0
#pragma unroll
    for (int p = 0; p < 4; p++) {
        GLD16(gA[p], &lds[0][dA[p]]);
        GLD16(gB[p], &lds[0][dB[p]]);
    }

    int cur = 0;
    for (int k0 = 0; k0 < DIMK; k0 += BK) {
        __syncthreads();               // lds[cur] staged; prior frag reads done
        if (k0 + BK < DIMK) {          // prefetch next tile into alternate buf
            int nk = k0 + BK;
#pragma unroll
            for (int p = 0; p < 4; p++) {
                GLD16(gA[p] + nk, &lds[cur ^ 1][dA[p]]);
                GLD16(gB[p] + nk, &lds[cur ^ 1][dB[p]]);
            }
        }
        const _Float16* sAh = &lds[cur][0];
        const _Float16* sAm = &lds[cur][4096];
        const _Float16* sBh = &lds[cur][8192];
        const _Float16* sBm = &lds[cur][12288];

        half8_t ah[4], am[4], bh[4], bm[4];
#pragma unroll
        for (int i = 0; i < 4; i++) {
            ah[i] = *(const half8_t*)(sAh + (wm * 4 + i) * 512 + lane * 8);
            am[i] = *(const half8_t*)(sAm + (wm * 4 + i) * 512 + lane * 8);
            bh[i] = *(const half8_t*)(sBh + (wn * 4 + i) * 512 + lane * 8);
            bm[i] = *(const half8_t*)(sBm + (wn * 4 + i) * 512 + lane * 8);
        }
        // product-major: consecutive MFMAs independent (16 between acc reuse)
#pragma unroll
        for (int i = 0; i < 4; i++)
#pragma unroll
            for (int j = 0; j < 4; j++)
                acc[i][j] = __builtin_amdgcn_mfma_f32_16x16x32_f16(am[i], bh[j], acc[i][j], 0, 0, 0);
#pragma unroll
        for (int i = 0; i < 4; i++)
#pragma unroll
            for (int j = 0; j < 4; j++)
                acc[i][j] = __builtin_amdgcn_mfma_f32_16x16x32_f16(ah[i], bm[j], acc[i][j], 0, 0, 0);
#pragma unroll
        for (int i = 0; i < 4; i++)
#pragma unroll
            for (int j = 0; j < 4; j++)
                acc[i][j] = __builtin_amdgcn_mfma_f32_16x16x32_f16(ah[i], bh[j], acc[i][j], 0, 0, 0);
        cur ^= 1;
    }

    // ---- per-row argmin over this wave's 64 cols ----
    // D layout: col = lane&15, row = (lane>>4)*4 + v   (m89/m91 verified)
    const int q  = lane >> 4;
    const int cl = lane & 15;
    float w2v[4];
    int   ncol[4];
#pragma unroll
    for (int j = 0; j < 4; j++) {
        ncol[j] = n0 + wn * 64 + j * 16 + cl;
        w2v[j]  = w2[ncol[j]];
    }
#pragma unroll
    for (int i = 0; i < 4; i++)
#pragma unroll
        for (int v = 0; v < 4; v++) {
            float bv = FLT_MAX;
            int   bi = 0x7FFFFFFF;
#pragma unroll
            for (int j = 0; j < 4; j++) {        // j ascending -> ties keep lower n
                float s = w2v[j] - 2.0f * acc[i][j][v];
                if (s < bv) { bv = s; bi = ncol[j]; }
            }
#pragma unroll
            for (int mask = 1; mask <= 8; mask <<= 1) {   // reduce over 16 col-lanes
                float ov = __shfl_xor(bv, mask);
                int   oi = __shfl_xor(bi, mask);
                if (ov < bv || (ov == bv && oi < bi)) { bv = ov; bi = oi; }
            }
            if (cl == 0) {
                int m = m0 + wm * 64 + i * 16 + q * 4 + v;
                int chunk = blockIdx.x * 2 + wn;
                pval[(size_t)m * NCHUNK + chunk] = bv;
                pidx[(size_t)m * NCHUNK + chunk] = bi;
            }
        }
}

// ---------------------------------------------------------------------------
// Epilogue v2: 2048 blocks x 2 rows. Butterfly argmin (all lanes hold the
// min), separable Gaussian tables in LDS, and NONTEMPORAL float4 stores for
// the 64MB output (written once, never re-read -> bypass L2 allocation).
// ---------------------------------------------------------------------------
__global__ __launch_bounds__(256) void epilogue_kernel(
        const float* __restrict__ pval, const int* __restrict__ pidx,
        const int* __restrict__ decay_p, const int* __restrict__ it_p,
        float* __restrict__ out) {
    __shared__ float tab[2][128];          // per local row: er[64] | ec[64]
    const int b    = blockIdx.x;           // handles rows 2b, 2b+1
    const int t    = threadIdx.x;
    const int lane = t & 63;
    const int w    = t >> 6;

    const float lr  = __expf(-(float)(*it_p) / (float)(*decay_p));
    const float so  = 32.0f * lr;          // SIGMA = 32
    const float inv = 1.0f / (so * so);

    if (w < 2) {                           // wave w reduces row 2b+w
        const int row = 2 * b + w;
        float v  = pval[(size_t)row * NCHUNK + lane];
        int   ii = pidx[(size_t)row * NCHUNK + lane];
#pragma unroll
        for (int mask = 1; mask <= 32; mask <<= 1) {
            float ov = __shfl_xor(v, mask);
            int   oi = __shfl_xor(ii, mask);
            if (ov < v || (ov == v && oi < ii)) { v = ov; ii = oi; }
        }
        const int r = ii >> 6, c = ii & 63;   // all lanes hold the min
        float dr = (float)(lane - r), dc = (float)(lane - c);
        tab[w][lane]      = __expf(-dr * dr * inv);
        tab[w][64 + lane] = __expf(-dc * dc * inv);
    }
    __syncthreads();

#pragma unroll
    for (int rr = 0; rr < 2; rr++) {
        const float* er = tab[rr];
        const float* ec = er + 64;
        f32x4* orow = (f32x4*)(out + (size_t)(2 * b + rr) * 4096);
#pragma unroll
        for (int qq = 0; qq < 4; qq++) {
            int f  = qq * 256 + t;         // float4 index in the 4096-row
            int i  = f >> 4;
            int j0 = (f & 15) * 4;
            float e = er[i];
            f32x4 o = {e * ec[j0], e * ec[j0 + 1],
                       e * ec[j0 + 2], e * ec[j0 + 3]};
            __builtin_nontemporal_store(o, orow + f);
        }
    }
}

// ---------------------------------------------------------------------------
extern "C" void kernel_launch(void* const* d_in, const int* in_sizes, int n_in,
                              void* d_out, int out_size, void* d_ws, size_t ws_size,
                              hipStream_t stream) {
    const float* X       = (const float*)d_in[0];   // [4096,512]
    const float* W       = (const float*)d_in[1];   // [4096,512]
    const int*   decay_p = (const int*)d_in[3];
    const int*   it_p    = (const int*)d_in[4];
    float* out = (float*)d_out;

    // ws: Xhi|Xmi|Whi|Wmi (4MB each f16) | w2 16KB | pval 1MB | pidx 1MB
    _Float16* Xhi = (_Float16*)d_ws;
    _Float16* Xmi = Xhi + (size_t)BATCH * DIMK;
    _Float16* Whi = Xmi + (size_t)BATCH * DIMK;
    _Float16* Wmi = Whi + (size_t)MN * DIMK;
    float*    w2  = (float*)(Wmi + (size_t)MN * DIMK);
    float*    pval = w2 + MN;
    int*      pidx = (int*)(pval + (size_t)BATCH * NCHUNK);

    convert_kernel<<<2048, 256, 0, stream>>>(X, W, Xhi, Xmi, Whi, Wmi, w2);
    score_kernel<<<dim3(32, 32), 256, 0, stream>>>(Xhi, Xmi, Whi, Wmi, w2, pval, pidx);
    epilogue_kernel<<<2048, 256, 0, stream>>>(pval, pidx, decay_p, it_p, out);
}